// Round 16
// baseline (772.434 us; speedup 1.0000x reference)
//
#include <hip/hip_runtime.h>
#include <math.h>

#define NB 32
#define CIN 512
#define HIDC 512
#define HP 28
#define PIX 784
#define NPCH 25
#define HS 112
#define HS2 12544
#define ATTH 64
#define BN_EPS 1e-5f

typedef unsigned short ushortT;
typedef __attribute__((ext_vector_type(8))) short s16x8;
typedef __attribute__((ext_vector_type(4))) float f32x4;

__device__ __forceinline__ float bf2f(unsigned bits16) {
    union { unsigned u; float f; } c; c.u = bits16 << 16; return c.f;
}
__device__ __forceinline__ unsigned f2bf_rne(float f) {
    union { float f; unsigned u; } c; c.f = f;
    unsigned u = c.u;
    u += 0x7FFFu + ((u >> 16) & 1u);
    return u >> 16;
}
__device__ __forceinline__ float asf_u(unsigned v) {
    union { unsigned u; float f; } c; c.u = v; return c.f;
}
__device__ __forceinline__ unsigned blendpair(unsigned u0, unsigned u1, unsigned u2,
                                              float a0, float a1, float a2) {
    float lo = a0*asf_u(u0 << 16) + a1*asf_u(u1 << 16) + a2*asf_u(u2 << 16);
    float hi = a0*asf_u(u0 & 0xFFFF0000u) + a1*asf_u(u1 & 0xFFFF0000u) + a2*asf_u(u2 & 0xFFFF0000u);
    union { float f; unsigned u; } cl, chh; cl.f = lo; chh.f = hi;
    return (cl.u >> 16) | (chh.u & 0xFFFF0000u);
}
__device__ __forceinline__ uint4 blend4(uint4 v0, uint4 v1, uint4 v2,
                                        float a0, float a1, float a2) {
    uint4 r;
    r.x = blendpair(v0.x, v1.x, v2.x, a0, a1, a2);
    r.y = blendpair(v0.y, v1.y, v2.y, a0, a1, a2);
    r.z = blendpair(v0.z, v1.z, v2.z, a0, a1, a2);
    r.w = blendpair(v0.w, v1.w, v2.w, a0, a1, a2);
    return r;
}

// ---------------------------------------------------------------------------
// NCHW f32 -> NHWC bf16 transpose (features)
// ---------------------------------------------------------------------------
__global__ __launch_bounds__(256)
void nchw2nhwc_bf16(const float* __restrict__ in, ushortT* __restrict__ out)
{
    __shared__ float tile[64][65];
    const int b  = blockIdx.z;
    const int c0 = blockIdx.y * 64;
    const int p0 = blockIdx.x * 64;
    const int tid = threadIdx.x;
    for (int i = tid; i < 4096; i += 256) {
        int cc = i >> 6, pp = i & 63;
        float v = 0.f;
        if (p0 + pp < PIX) v = in[((size_t)b*CIN + c0 + cc)*PIX + p0 + pp];
        tile[cc][pp] = v;
    }
    __syncthreads();
    for (int i = tid; i < 4096; i += 256) {
        int pp = i >> 6, cc = i & 63;
        if (p0 + pp < PIX)
            out[((size_t)b*PIX + p0 + pp)*CIN + c0 + cc] = (ushortT)f2bf_rne(tile[cc][pp]);
    }
}

// ---------------------------------------------------------------------------
// weight transform: OIHW f32 -> [slot][tap][oc][ic] bf16
// ---------------------------------------------------------------------------
__device__ __forceinline__ void wtrans_body(const float* __restrict__ src,
                                            ushortT* __restrict__ dst_slot,
                                            int oc, int tid)
{
    __shared__ float buf[4608];
    for (int i = tid; i < 4608; i += 256) buf[i] = src[i];
    __syncthreads();
    for (int i = tid; i < 4608; i += 256) {
        int t = i / 512, ic = i - t*512;
        dst_slot[((size_t)t*HIDC + oc)*CIN + ic] = (ushortT)f2bf_rne(buf[(size_t)ic*9 + t]);
    }
}

__global__ __launch_bounds__(256)
void wtrans_kernel(const float* __restrict__ w, ushortT* __restrict__ wt)
{
    const int oc = blockIdx.x, bank = blockIdx.y;
    wtrans_body(w + ((size_t)bank*HIDC + oc)*CIN*9,
                wt + (size_t)bank*9*HIDC*CIN, oc, threadIdx.x);
}

__global__ __launch_bounds__(256)
void wtrans2_kernel(const float* __restrict__ w0, const float* __restrict__ w1,
                    ushortT* __restrict__ wt)
{
    const int oc = blockIdx.x, slot = blockIdx.y;
    const float* w = slot ? w1 : w0;
    wtrans_body(w + (size_t)oc*CIN*9, wt + (size_t)slot*9*HIDC*CIN, oc, threadIdx.x);
}

// ---------------------------------------------------------------------------
// MFMA conv 3x3 SAME. NHWC bf16 in.  (round-6 structure + XCD affinity)
// Tile: 64 oc x 392 pix (14-row strip). 4 waves = 4 pixel quarters (98 pix).
// Wave: all 64 oc (mf=4 A-frags) x 7 B-frags -> 22 LDS reads / 56 MFMA per tap.
// XOR-swizzled LDS, 2-uint4 reg-prefetch weight dbuf, single barrier per tap.
// 1-D 512-block grid, XCD-affinity decode (8 x-strip siblings -> same XCD).
// s_setprio(1) around MFMA cluster: 2 independent blocks/CU give wave-phase
// diversity, letting MFMA-phase waves win issue arbitration (T5).
// MODE 0: +bias, relu -> bf16 NHWC
// MODE 1: dyn blend, bn, relu -> bf16 NHWC
// MODE 2: dyn blend, bn, +identity(NHWC bf16), relu -> f32 NCHW
// ---------------------------------------------------------------------------
template<int MODE>
__global__ __launch_bounds__(256, 2)
void conv_mfma(const ushortT* __restrict__ xin,
               const ushortT* __restrict__ wt,
               const float* __restrict__ bias,
               const float* __restrict__ scale,
               const float* __restrict__ shift,
               const float* __restrict__ att,
               const ushortT* __restrict__ addsrc,
               ushortT* __restrict__ outb,
               float* __restrict__ outf)
{
    __shared__ __align__(16) ushortT xs[480*64];     // 61,440 B (16 rows x 30 cols)
    __shared__ __align__(16) ushortT wsA[2][4096];   // dbuf [64 oc][64 ic], swizzled

    const int tid  = threadIdx.x;
    const int lane = tid & 63;
    const int ph   = tid >> 6;        // wave = pixel quarter (0..3)
    const int lrow = lane & 15;
    const int lgrp = lane >> 4;

    const int bid = blockIdx.x;       // 512 blocks, 1-D
    const int oct = bid >> 6;
    const int g   = bid & 63;         // g%8 == XCD for all 8 octile siblings
    const int b   = g >> 1;
    const int sh  = g & 1;
    const int oc0 = oct * 64;

    float a0 = 0.f, a1 = 0.f, a2 = 0.f;
    if (MODE != 0) { a0 = att[b*3+0]; a1 = att[b*3+1]; a2 = att[b*3+2]; }

    int pq[7];
#pragma unroll
    for (int nf = 0; nf < 7; ++nf) {
        int q = ph*98 + nf*16 + lrow;
        int qc = q < 392 ? q : 391;
        int r = qc / 28;
        pq[nf] = r*30 + (qc - r*28);
    }

    int afoff[2][4];
#pragma unroll
    for (int kk = 0; kk < 2; ++kk)
#pragma unroll
        for (int mf = 0; mf < 4; ++mf) {
            int ocl = mf*16 + lrow;
            afoff[kk][mf] = (ocl*8 + ((kk*4+lgrp) ^ (ocl&7)))*8;
        }

    int woff[2], wdst[2];
#pragma unroll
    for (int i = 0; i < 2; ++i) {
        int j = tid + i*256;
        int ocl = j >> 3, o = j & 7;
        woff[i] = ocl*CIN + o*8;
        wdst[i] = (ocl*8 + (o ^ (ocl&7)))*8;
    }

    f32x4 acc[4][7];
#pragma unroll
    for (int mf = 0; mf < 4; ++mf)
#pragma unroll
        for (int nf = 0; nf < 7; ++nf) acc[mf][nf] = (f32x4)0.f;

    const ushortT* xb = xin + (size_t)b * PIX * CIN;
    const size_t BANKS = (size_t)9*HIDC*CIN;

    auto stage_x = [&](int ic0) {
#pragma unroll
        for (int i = 0; i < 15; ++i) {
            int j = tid + i*256;           // 3840 = 15*256 exact
            int p = j >> 3, o = j & 7;
            int row = p / 30, col = p - row*30;
            int gh = sh*14 + row - 1, gw = col - 1;
            uint4 val = make_uint4(0u,0u,0u,0u);
            if ((unsigned)gh < 28u && (unsigned)gw < 28u)
                val = *(const uint4*)(xb + ((size_t)(gh*28 + gw)*CIN + ic0 + o*8));
            *(uint4*)(xs + (size_t)((p*8 + (o ^ (p&7)))*8)) = val;
        }
    };

    // ---- prologue: stage x(ch0) and weights(k=0) ----
    stage_x(0);
    {
        const ushortT* wA = wt + (size_t)oc0*CIN;    // tap 0, ic-chunk 0
#pragma unroll
        for (int i = 0; i < 2; ++i) {
            uint4 v0 = *(const uint4*)(wA + woff[i]);
            uint4 val = v0;
            if (MODE != 0) {
                uint4 v1 = *(const uint4*)(wA + woff[i] + BANKS);
                uint4 v2 = *(const uint4*)(wA + woff[i] + 2*BANKS);
                val = blend4(v0, v1, v2, a0, a1, a2);
            }
            *(uint4*)(&wsA[0][0] + wdst[i]) = val;
        }
    }
    __syncthreads();

    // ---- main K-loop: 72 steps ----
    uint4 p0[2], p1[2], p2[2];
    for (int k = 0; k < 72; ++k) {
        const int ch  = k / 9;
        const int t   = k - ch*9;
        const int cur = k & 1;
        const bool pf = (k < 71);
        const int kn  = k + 1;
        const int chn = kn / 9, tn = kn - chn*9;

        if (pf) {
            const ushortT* wA = wt + ((size_t)tn*HIDC + oc0)*CIN + chn*64;
#pragma unroll
            for (int i = 0; i < 2; ++i) {
                p0[i] = *(const uint4*)(wA + woff[i]);
                if (MODE != 0) {
                    p1[i] = *(const uint4*)(wA + woff[i] + BANKS);
                    p2[i] = *(const uint4*)(wA + woff[i] + 2*BANKS);
                }
            }
        }

        const int dh = (t >= 6) ? 2 : (t >= 3 ? 1 : 0);
        const int dw = t - dh*3;
        const int doff = dh*30 + dw;
        const ushortT* wbuf = &wsA[cur][0];
        __builtin_amdgcn_s_setprio(1);
#pragma unroll
        for (int kk = 0; kk < 2; ++kk) {
            const int ob = kk*4 + lgrp;
            s16x8 af[4];
#pragma unroll
            for (int mf = 0; mf < 4; ++mf)
                af[mf] = *(const s16x8*)(wbuf + afoff[kk][mf]);
#pragma unroll
            for (int nf = 0; nf < 7; ++nf) {
                int pp = pq[nf] + doff;
                s16x8 bv = *(const s16x8*)(xs + (size_t)((pp*8 + (ob ^ (pp&7)))*8));
#pragma unroll
                for (int mf = 0; mf < 4; ++mf)
                    acc[mf][nf] = __builtin_amdgcn_mfma_f32_16x16x32_bf16(af[mf], bv, acc[mf][nf], 0, 0, 0);
            }
        }
        __builtin_amdgcn_s_setprio(0);

        if (pf) {
            ushortT* wb = &wsA[cur^1][0];
#pragma unroll
            for (int i = 0; i < 2; ++i) {
                uint4 val;
                if (MODE == 0) val = p0[i];
                else           val = blend4(p0[i], p1[i], p2[i], a0, a1, a2);
                *(uint4*)(wb + wdst[i]) = val;
            }
            if (t == 8) {
                __syncthreads();
                stage_x(chn*64);
            }
        }
        __syncthreads();
    }

    // ---- epilogue ----
    const int q0 = ph * 98;
#pragma unroll
    for (int mf = 0; mf < 4; ++mf) {
        const int oc = oc0 + mf*16 + lgrp*4;
        float sc[4], shv[4];
#pragma unroll
        for (int jj = 0; jj < 4; ++jj) {
            if (MODE == 0) { sc[jj] = 1.f; shv[jj] = bias[oc+jj]; }
            else           { sc[jj] = scale[oc+jj]; shv[jj] = shift[oc+jj]; }
        }
#pragma unroll
        for (int nf = 0; nf < 7; ++nf) {
            const int qrel = nf*16 + lrow;
            if (qrel < 98) {
                const int p = sh*392 + q0 + qrel;
                f32x4 a = acc[mf][nf];
                if (MODE == 2) {
                    const ushortT* id = addsrc + ((size_t)b*PIX + p)*CIN + oc;
                    ushort4 iv = *(const ushort4*)id;
                    float v0 = fmaxf(a.x*sc[0] + shv[0] + bf2f(iv.x), 0.f);
                    float v1 = fmaxf(a.y*sc[1] + shv[1] + bf2f(iv.y), 0.f);
                    float v2 = fmaxf(a.z*sc[2] + shv[2] + bf2f(iv.z), 0.f);
                    float v3 = fmaxf(a.w*sc[3] + shv[3] + bf2f(iv.w), 0.f);
                    float* op = outf + ((size_t)b*HIDC + oc)*PIX + p;
                    op[0*PIX] = v0; op[1*PIX] = v1; op[2*PIX] = v2; op[3*PIX] = v3;
                } else {
                    float v0 = fmaxf(a.x*sc[0] + shv[0], 0.f);
                    float v1 = fmaxf(a.y*sc[1] + shv[1], 0.f);
                    float v2 = fmaxf(a.z*sc[2] + shv[2], 0.f);
                    float v3 = fmaxf(a.w*sc[3] + shv[3], 0.f);
                    ushort4 o4;
                    o4.x = (ushortT)f2bf_rne(v0); o4.y = (ushortT)f2bf_rne(v1);
                    o4.z = (ushortT)f2bf_rne(v2); o4.w = (ushortT)f2bf_rne(v3);
                    *(ushort4*)(outb + ((size_t)b*PIX + p)*CIN + oc) = o4;
                }
            }
        }
    }
}

// ---------------------------------------------------------------------------
// fallback f32 direct conv (used only if ws_size too small)
// ---------------------------------------------------------------------------
template<int MODE>
__global__ __launch_bounds__(256)
void conv3x3_kernel(const float* __restrict__ x,
                    const float* __restrict__ w,
                    const float* __restrict__ bias,
                    const float* __restrict__ att,
                    const float* __restrict__ bnscale,
                    const float* __restrict__ bnshift,
                    const float* __restrict__ addsrc,
                    float* __restrict__ out)
{
    const int tid = threadIdx.x;
    const int o0  = blockIdx.x * 8;
    const int b   = blockIdx.y;
    __shared__ float xsb[30*30];
    __shared__ float wsm[72];
    float a0 = 0.f, a1 = 0.f, a2 = 0.f;
    if (MODE != 0) { a0 = att[b*3+0]; a1 = att[b*3+1]; a2 = att[b*3+2]; }
    float acc[8][4];
#pragma unroll
    for (int o = 0; o < 8; ++o)
#pragma unroll
        for (int s = 0; s < 4; ++s) acc[o][s] = 0.f;
    const float* xbp = x + (size_t)b * CIN * PIX;
    for (int i = 0; i < CIN; ++i) {
        const float* xc = xbp + (size_t)i * PIX;
        for (int idx = tid; idx < 900; idx += 256) {
            int r = idx / 30, c = idx - r*30;
            float v = 0.f;
            if (r >= 1 && r <= HP && c >= 1 && c <= HP) v = xc[(r-1)*HP + (c-1)];
            xsb[idx] = v;
        }
        if (tid < 72) {
            int o = tid / 9, tap = tid - o*9;
            float wv;
            if (MODE == 0) wv = w[((size_t)(o0+o)*CIN + i)*9 + tap];
            else {
                size_t base = ((size_t)(o0+o)*CIN + i)*9 + tap;
                size_t bank = (size_t)HIDC*CIN*9;
                wv = a0*w[base] + a1*w[base+bank] + a2*w[base+2*bank];
            }
            wsm[tid] = wv;
        }
        __syncthreads();
        float xwin[4][9];
#pragma unroll
        for (int s = 0; s < 4; ++s) {
            int p = tid + s*256; if (p > PIX-1) p = PIX-1;
            int h = p / HP, wc = p - h*HP;
#pragma unroll
            for (int t = 0; t < 9; ++t) {
                int dh = t/3, dw = t - dh*3;
                xwin[s][t] = xsb[(h+dh)*30 + (wc+dw)];
            }
        }
#pragma unroll
        for (int o = 0; o < 8; ++o) {
            float wr[9];
#pragma unroll
            for (int t = 0; t < 9; ++t) wr[t] = wsm[o*9+t];
#pragma unroll
            for (int s = 0; s < 4; ++s) {
                float sum = acc[o][s];
#pragma unroll
                for (int t = 0; t < 9; ++t) sum = fmaf(wr[t], xwin[s][t], sum);
                acc[o][s] = sum;
            }
        }
        __syncthreads();
    }
#pragma unroll
    for (int s = 0; s < 4; ++s) {
        int p = tid + s*256;
        if (p >= PIX) continue;
#pragma unroll
        for (int o = 0; o < 8; ++o) {
            int oc = o0 + o;
            float v = acc[o][s];
            if (MODE == 0) v += bias[oc];
            else           v = v * bnscale[oc] + bnshift[oc];
            if (MODE == 2) v += addsrc[((size_t)b*HIDC + oc)*PIX + p];
            v = fmaxf(v, 0.f);
            out[((size_t)b*HIDC + oc)*PIX + p] = v;
        }
    }
}

// ---------------------------------------------------------------------------
// statistics branch: stat1 fused with cls, single pass (25 vals in regs)
// ---------------------------------------------------------------------------
__global__ __launch_bounds__(256)
void stat1cls_kernel(const float* __restrict__ fs, float* __restrict__ part,
                     int* __restrict__ cls)
{
    const int b = blockIdx.y, chunk = blockIdx.x, tid = threadIdx.x;
    const float* f = fs + (size_t)b * NPCH * HS2;
    const int lo = chunk * 14 * HS, hi = lo + 14 * HS;
    float s0=0.f, s1=0.f, s2=0.f, s3=0.f;
    for (int pos = lo + tid; pos < hi; pos += 256) {
        float f25[NPCH];
#pragma unroll
        for (int c = 0; c < NPCH; ++c) f25[c] = f[(size_t)c*HS2 + pos];
        float t0=-1e30f, t1=-1e30f, t2=-1e30f, t3=-1e30f;
        int bi = 0;
#pragma unroll
        for (int c = 0; c < NPCH; ++c) {
            float v = f25[c];
            if      (v > t0) { t3=t2; t2=t1; t1=t0; t0=v; bi=c; }
            else if (v > t1) { t3=t2; t2=t1; t1=v; }
            else if (v > t2) { t3=t2; t2=v; }
            else if (v > t3) { t3=v; }
        }
        cls[(size_t)b*HS2 + pos] = bi;
        float denom = 0.f;
#pragma unroll
        for (int c = 0; c < NPCH; ++c) denom += expf(f25[c] - t0);
        float inv = 1.f / denom;
        s0 += inv;
        s1 += expf(t1 - t0) * inv;
        s2 += expf(t2 - t0) * inv;
        s3 += expf(t3 - t0) * inv;
    }
    __shared__ float red[256];
    float vals[4] = {s0, s1, s2, s3};
    for (int j = 0; j < 4; ++j) {
        red[tid] = vals[j];
        __syncthreads();
        for (int off = 128; off; off >>= 1) {
            if (tid < off) red[tid] += red[tid + off];
            __syncthreads();
        }
        if (tid == 0) part[((size_t)b*8 + chunk)*4 + j] = red[0];
        __syncthreads();
    }
}

// fused row+col masked-std stats
#define RB 21504
#define CB 336
__global__ __launch_bounds__(256)
void rowcolstat_kernel(const float* __restrict__ u, const float* __restrict__ v,
                       const int* __restrict__ cls,
                       float* __restrict__ uvar, float* __restrict__ vvar)
{
    if (blockIdx.x < RB) {
        int wid = blockIdx.x*4 + (threadIdx.x >> 6);
        int lane = threadIdx.x & 63;
        int h = wid % HS, t = wid / HS, c = t % 24, b = t / 24;
        const int*   cr = cls + (size_t)b*HS2 + (size_t)h*HS;
        const float* ur = u + (((size_t)b*NPCH + c + 1)*HS + h)*HS;
        float cnt = 0.f, s = 0.f, s2 = 0.f;
        for (int wc = lane; wc < HS; wc += 64) {
            if (cr[wc] == c + 1) { float vv = ur[wc]; cnt += 1.f; s += vv; s2 += vv*vv; }
        }
        for (int off = 32; off; off >>= 1) {
            cnt += __shfl_down(cnt, off);
            s   += __shfl_down(s, off);
            s2  += __shfl_down(s2, off);
        }
        if (lane == 0) {
            float mean = s / cnt;
            uvar[wid] = sqrtf(fmaxf(s2/cnt - mean*mean, 0.f));
        }
    } else {
        int idx = (blockIdx.x - RB)*256 + threadIdx.x;
        if (idx >= NB*24*HS) return;
        int wc = idx % HS, t = idx / HS, c = t % 24, b = t / 24;
        const int*   cbase = cls + (size_t)b*HS2 + wc;
        const float* vbase = v + (((size_t)b*NPCH + c + 1)*HS)*HS + wc;
        float cnt = 0.f, s = 0.f, s2 = 0.f;
        for (int h = 0; h < HS; ++h) {
            if (cbase[(size_t)h*HS] == c + 1) {
                float val = vbase[(size_t)h*HS];
                cnt += 1.f; s += val; s2 += val*val;
            }
        }
        float mean = s / cnt;
        vvar[idx] = sqrtf(fmaxf(s2/cnt - mean*mean, 0.f));
    }
}

// partial over 8 position segments -> pooled2p[b*8+seg] (sum, undivided)
__global__ __launch_bounds__(256)
void stat2_kernel(const float* __restrict__ uvar, const float* __restrict__ vvar,
                  float* __restrict__ pooled2p)
{
    const int b = blockIdx.x, seg = blockIdx.y, tid = threadIdx.x;
    __shared__ float us[24*HS], vs[24*HS], red[256];
    for (int i = tid; i < 24*HS; i += 256) {
        us[i] = uvar[(size_t)b*24*HS + i];
        vs[i] = vvar[(size_t)b*24*HS + i];
    }
    __syncthreads();
    float local = 0.f;
    const int lo = seg*1568, hi = lo + 1568;
    for (int pos = lo + tid; pos < hi; pos += 256) {
        int h = pos / HS, wc = pos - h*HS;
        float sum = 0.f;
        for (int c = 0; c < 24; ++c) sum += sqrtf(us[c*HS+h] * vs[c*HS+wc]);
        local += expf(-sum);
    }
    red[tid] = local;
    __syncthreads();
    for (int off = 128; off; off >>= 1) {
        if (tid < off) red[tid] += red[tid + off];
        __syncthreads();
    }
    if (tid == 0) pooled2p[b*8 + seg] = red[0];
}

__global__ __launch_bounds__(256)
void mlp_kernel(const float* __restrict__ part, const float* __restrict__ pooled2p,
                const float* __restrict__ a1w1, const float* __restrict__ a1b1,
                const float* __restrict__ a1w2, const float* __restrict__ a1b2,
                const float* __restrict__ a2w1, const float* __restrict__ a2b1,
                const float* __restrict__ a2w2, const float* __restrict__ a2b2,
                const float* __restrict__ bn1g, const float* __restrict__ bn1b,
                const float* __restrict__ bn1m, const float* __restrict__ bn1v,
                const float* __restrict__ bn2g, const float* __restrict__ bn2b,
                const float* __restrict__ bn2m, const float* __restrict__ bn2v,
                float* __restrict__ att1, float* __restrict__ att2,
                float* __restrict__ bnsc)
{
    const int tid = threadIdx.x;
    if (tid < NB) {
        int b = tid;
        float p[5]; float tot = 0.f;
        for (int j = 0; j < 4; ++j) {
            float s = 0.f;
            for (int ch = 0; ch < 8; ++ch) s += part[((size_t)b*8 + ch)*4 + j];
            p[j] = s / (float)HS2; tot += p[j];
        }
        p[4] = tot * 0.25f;
        float lg[3] = {a1b2[0], a1b2[1], a1b2[2]};
        for (int j = 0; j < ATTH; ++j) {
            float hv = a1b1[j];
            for (int t = 0; t < 5; ++t) hv += a1w1[j*5+t] * p[t];
            hv = fmaxf(hv, 0.f);
            for (int k = 0; k < 3; ++k) lg[k] += a1w2[k*ATTH+j] * hv;
        }
        float mx = fmaxf(fmaxf(lg[0], lg[1]), lg[2]);
        float e0 = expf(lg[0]-mx), e1 = expf(lg[1]-mx), e2 = expf(lg[2]-mx);
        float inv = 1.f / (e0+e1+e2);
        att1[b*3+0] = e0*inv; att1[b*3+1] = e1*inv; att1[b*3+2] = e2*inv;
    } else if (tid < 2*NB) {
        int b = tid - NB;
        float psum = 0.f;
        for (int j = 0; j < 8; ++j) psum += pooled2p[b*8 + j];
        float p = psum / (float)HS2;
        float lg[3] = {a2b2[0], a2b2[1], a2b2[2]};
        for (int j = 0; j < ATTH; ++j) {
            float hv = fmaxf(a2b1[j] + a2w1[j] * p, 0.f);
            for (int k = 0; k < 3; ++k) lg[k] += a2w2[k*ATTH+j] * hv;
        }
        float mx = fmaxf(fmaxf(lg[0], lg[1]), lg[2]);
        float e0 = expf(lg[0]-mx), e1 = expf(lg[1]-mx), e2 = expf(lg[2]-mx);
        float inv = 1.f / (e0+e1+e2);
        att2[b*3+0] = e0*inv; att2[b*3+1] = e1*inv; att2[b*3+2] = e2*inv;
    }
    for (int o = tid; o < HIDC; o += 256) {
        float sc1 = bn1g[o] / sqrtf(bn1v[o] + BN_EPS);
        bnsc[o]          = sc1;
        bnsc[512 + o]    = bn1b[o] - bn1m[o]*sc1;
        float sc2 = bn2g[o] / sqrtf(bn2v[o] + BN_EPS);
        bnsc[1024 + o]   = sc2;
        bnsc[1536 + o]   = bn2b[o] - bn2m[o]*sc2;
    }
}

// ---------------------------------------------------------------------------
extern "C" void kernel_launch(void* const* d_in, const int* in_sizes, int n_in,
                              void* d_out, int out_size, void* d_ws, size_t ws_size,
                              hipStream_t stream)
{
    (void)in_sizes; (void)n_in; (void)out_size;
    const float* features = (const float*)d_in[0];
    const float* fine_segm= (const float*)d_in[1];
    const float* u        = (const float*)d_in[2];
    const float* v        = (const float*)d_in[3];
    const float* conv1_w  = (const float*)d_in[4];
    const float* conv1_b  = (const float*)d_in[5];
    const float* conv2_w  = (const float*)d_in[6];
    const float* conv2_b  = (const float*)d_in[7];
    const float* a1w1     = (const float*)d_in[8];
    const float* a1b1     = (const float*)d_in[9];
    const float* a1w2     = (const float*)d_in[10];
    const float* a1b2     = (const float*)d_in[11];
    const float* dyn1_w   = (const float*)d_in[12];
    const float* a2w1     = (const float*)d_in[13];
    const float* a2b1     = (const float*)d_in[14];
    const float* a2w2     = (const float*)d_in[15];
    const float* a2b2     = (const float*)d_in[16];
    const float* dyn2_w   = (const float*)d_in[17];
    const float* bn1g     = (const float*)d_in[18];
    const float* bn1b     = (const float*)d_in[19];
    const float* bn1m     = (const float*)d_in[20];
    const float* bn1v     = (const float*)d_in[21];
    const float* bn2g     = (const float*)d_in[22];
    const float* bn2b     = (const float*)d_in[23];
    const float* bn2m     = (const float*)d_in[24];
    const float* bn2v     = (const float*)d_in[25];

    const size_t XB_BYTES = (size_t)NB*PIX*CIN*2;        // 25,690,112
    const size_t WT_BYTES = (size_t)3*9*HIDC*CIN*2;      // 14,155,776
    const size_t NEED = XB_BYTES*2 + WT_BYTES + 2308096;
    const size_t WSLOT = (size_t)9*HIDC*CIN;             // elements per slot

    if (ws_size >= NEED) {
        char* wsb = (char*)d_ws;
        ushortT* xbuf = (ushortT*)wsb;                      // features NHWC, then y1
        ushortT* x2   = (ushortT*)(wsb + XB_BYTES);         // identity
        ushortT* wt   = (ushortT*)(wsb + 2*XB_BYTES);       // transformed weights (3 slots)
        float* sm     = (float*)(wsb + 2*XB_BYTES + WT_BYTES);
        float* part    = sm;  sm += 1024;
        float* pooled2 = sm;  sm += 256;
        float* att1    = sm;  sm += 96;
        float* att2    = sm;  sm += 96;
        float* bnsc    = sm;  sm += 2048;
        float* uvar    = sm;  sm += NB*24*HS;
        float* vvar    = sm;  sm += NB*24*HS;
        int*   cls     = (int*)sm;
        ushortT* x1    = (ushortT*)d_out;   // 25.7MB scratch inside 51.4MB d_out

        // conv backbone front half (XCD-affinity 1-D grid)
        nchw2nhwc_bf16<<<dim3(13, 8, NB), 256, 0, stream>>>(features, xbuf);
        wtrans2_kernel<<<dim3(512, 2), 256, 0, stream>>>(conv1_w, conv2_w, wt);
        conv_mfma<0><<<512, 256, 0, stream>>>(
            xbuf, wt, conv1_b, nullptr, nullptr, nullptr, nullptr, x1, nullptr);
        conv_mfma<0><<<512, 256, 0, stream>>>(
            x1, wt + WSLOT, conv2_b, nullptr, nullptr, nullptr, nullptr, x2, nullptr);

        // statistics branch
        stat1cls_kernel<<<dim3(8, NB), 256, 0, stream>>>(fine_segm, part, cls);
        rowcolstat_kernel<<<RB + CB, 256, 0, stream>>>(u, v, cls, uvar, vvar);
        stat2_kernel<<<dim3(NB, 8), 256, 0, stream>>>(uvar, vvar, pooled2);
        mlp_kernel<<<1, 256, 0, stream>>>(part, pooled2,
            a1w1, a1b1, a1w2, a1b2, a2w1, a2b1, a2w2, a2b2,
            bn1g, bn1b, bn1m, bn1v, bn2g, bn2b, bn2m, bn2v,
            att1, att2, bnsc);

        // dynamic convs (XCD-affinity 1-D grid)
        wtrans_kernel<<<dim3(512, 3), 256, 0, stream>>>(dyn1_w, wt);
        conv_mfma<1><<<512, 256, 0, stream>>>(
            x2, wt, nullptr, bnsc, bnsc + 512, att1, nullptr, xbuf, nullptr);
        wtrans_kernel<<<dim3(512, 3), 256, 0, stream>>>(dyn2_w, wt);
        conv_mfma<2><<<512, 256, 0, stream>>>(
            xbuf, wt, nullptr, bnsc + 1024, bnsc + 1536, att2, x2, nullptr, (float*)d_out);
    } else {
        // fallback: f32 direct path
        const size_t BIG = (size_t)NB * HIDC * PIX;
        float* x1y1 = (float*)d_out;
        float* ws0  = (float*)d_ws;
        float* sm   = ws0 + BIG;
        float* part    = sm;  sm += 1024;
        float* pooled2 = sm;  sm += 256;
        float* att1    = sm;  sm += 96;
        float* att2    = sm;  sm += 96;
        float* bnsc    = sm;  sm += 2048;
        float* uvar    = sm;  sm += NB*24*HS;
        float* vvar    = sm;  sm += NB*24*HS;
        int*   cls     = (int*)sm;

        conv3x3_kernel<0><<<dim3(64, NB), 256, 0, stream>>>(
            features, conv1_w, conv1_b, nullptr, nullptr, nullptr, nullptr, x1y1);
        conv3x3_kernel<0><<<dim3(64, NB), 256, 0, stream>>>(
            x1y1, conv2_w, conv2_b, nullptr, nullptr, nullptr, nullptr, ws0);
        stat1cls_kernel<<<dim3(8, NB), 256, 0, stream>>>(fine_segm, part, cls);
        rowcolstat_kernel<<<RB + CB, 256, 0, stream>>>(u, v, cls, uvar, vvar);
        stat2_kernel<<<dim3(NB, 8), 256, 0, stream>>>(uvar, vvar, pooled2);
        mlp_kernel<<<1, 256, 0, stream>>>(part, pooled2,
            a1w1, a1b1, a1w2, a1b2, a2w1, a2b1, a2w2, a2b2,
            bn1g, bn1b, bn1m, bn1v, bn2g, bn2b, bn2m, bn2v,
            att1, att2, bnsc);
        conv3x3_kernel<1><<<dim3(64, NB), 256, 0, stream>>>(
            ws0, dyn1_w, nullptr, att1, bnsc, bnsc + 512, nullptr, x1y1);
        conv3x3_kernel<2><<<dim3(64, NB), 256, 0, stream>>>(
            x1y1, dyn2_w, nullptr, att2, bnsc + 1024, bnsc + 1536, ws0, ws0);
        hipMemcpyAsync(d_out, ws0, BIG * sizeof(float), hipMemcpyDeviceToDevice, stream);
    }
}

// Round 17
// 738.212 us; speedup vs baseline: 1.0464x; 1.0464x over previous
//
#include <hip/hip_runtime.h>
#include <math.h>

#define NB 32
#define CIN 512
#define HIDC 512
#define HP 28
#define PIX 784
#define NPCH 25
#define HS 112
#define HS2 12544
#define ATTH 64
#define BN_EPS 1e-5f

typedef unsigned short ushortT;
typedef __attribute__((ext_vector_type(8))) short s16x8;
typedef __attribute__((ext_vector_type(4))) float f32x4;

__device__ __forceinline__ float bf2f(unsigned bits16) {
    union { unsigned u; float f; } c; c.u = bits16 << 16; return c.f;
}
__device__ __forceinline__ unsigned f2bf_rne(float f) {
    union { float f; unsigned u; } c; c.f = f;
    unsigned u = c.u;
    u += 0x7FFFu + ((u >> 16) & 1u);
    return u >> 16;
}
__device__ __forceinline__ float asf_u(unsigned v) {
    union { unsigned u; float f; } c; c.u = v; return c.f;
}
__device__ __forceinline__ unsigned blendpair(unsigned u0, unsigned u1, unsigned u2,
                                              float a0, float a1, float a2) {
    float lo = a0*asf_u(u0 << 16) + a1*asf_u(u1 << 16) + a2*asf_u(u2 << 16);
    float hi = a0*asf_u(u0 & 0xFFFF0000u) + a1*asf_u(u1 & 0xFFFF0000u) + a2*asf_u(u2 & 0xFFFF0000u);
    union { float f; unsigned u; } cl, chh; cl.f = lo; chh.f = hi;
    return (cl.u >> 16) | (chh.u & 0xFFFF0000u);
}
__device__ __forceinline__ uint4 blend4(uint4 v0, uint4 v1, uint4 v2,
                                        float a0, float a1, float a2) {
    uint4 r;
    r.x = blendpair(v0.x, v1.x, v2.x, a0, a1, a2);
    r.y = blendpair(v0.y, v1.y, v2.y, a0, a1, a2);
    r.z = blendpair(v0.z, v1.z, v2.z, a0, a1, a2);
    r.w = blendpair(v0.w, v1.w, v2.w, a0, a1, a2);
    return r;
}

// ---------------------------------------------------------------------------
// NCHW f32 -> NHWC bf16 transpose (features)
// ---------------------------------------------------------------------------
__global__ __launch_bounds__(256)
void nchw2nhwc_bf16(const float* __restrict__ in, ushortT* __restrict__ out)
{
    __shared__ float tile[64][65];
    const int b  = blockIdx.z;
    const int c0 = blockIdx.y * 64;
    const int p0 = blockIdx.x * 64;
    const int tid = threadIdx.x;
    for (int i = tid; i < 4096; i += 256) {
        int cc = i >> 6, pp = i & 63;
        float v = 0.f;
        if (p0 + pp < PIX) v = in[((size_t)b*CIN + c0 + cc)*PIX + p0 + pp];
        tile[cc][pp] = v;
    }
    __syncthreads();
    for (int i = tid; i < 4096; i += 256) {
        int pp = i >> 6, cc = i & 63;
        if (p0 + pp < PIX)
            out[((size_t)b*PIX + p0 + pp)*CIN + c0 + cc] = (ushortT)f2bf_rne(tile[cc][pp]);
    }
}

// ---------------------------------------------------------------------------
// weight transform: OIHW f32 -> [slot][tap][oc][ic] bf16
// ---------------------------------------------------------------------------
__device__ __forceinline__ void wtrans_body(const float* __restrict__ src,
                                            ushortT* __restrict__ dst_slot,
                                            int oc, int tid)
{
    __shared__ float buf[4608];
    for (int i = tid; i < 4608; i += 256) buf[i] = src[i];
    __syncthreads();
    for (int i = tid; i < 4608; i += 256) {
        int t = i / 512, ic = i - t*512;
        dst_slot[((size_t)t*HIDC + oc)*CIN + ic] = (ushortT)f2bf_rne(buf[(size_t)ic*9 + t]);
    }
}

__global__ __launch_bounds__(256)
void wtrans_kernel(const float* __restrict__ w, ushortT* __restrict__ wt)
{
    const int oc = blockIdx.x, bank = blockIdx.y;
    wtrans_body(w + ((size_t)bank*HIDC + oc)*CIN*9,
                wt + (size_t)bank*9*HIDC*CIN, oc, threadIdx.x);
}

__global__ __launch_bounds__(256)
void wtrans2_kernel(const float* __restrict__ w0, const float* __restrict__ w1,
                    ushortT* __restrict__ wt)
{
    const int oc = blockIdx.x, slot = blockIdx.y;
    const float* w = slot ? w1 : w0;
    wtrans_body(w + (size_t)oc*CIN*9, wt + (size_t)slot*9*HIDC*CIN, oc, threadIdx.x);
}

// ---------------------------------------------------------------------------
// MFMA conv 3x3 SAME. NHWC bf16 in.  (round-15 best: r6 structure + XCD aff.)
// Tile: 64 oc x 392 pix (14-row strip). 4 waves = 4 pixel quarters (98 pix).
// Wave: all 64 oc (mf=4 A-frags) x 7 B-frags -> 22 LDS reads / 56 MFMA per tap.
// XOR-swizzled LDS, 2-uint4 reg-prefetch weight dbuf, single barrier per tap.
// 1-D 512-block grid, XCD-affinity decode (8 x-strip siblings -> same XCD).
// NOTE: s_setprio around MFMA measured -21% here (R16) — do not re-add.
// MODE 0: +bias, relu -> bf16 NHWC
// MODE 1: dyn blend, bn, relu -> bf16 NHWC
// MODE 2: dyn blend, bn, +identity(NHWC bf16), relu -> f32 NCHW
// ---------------------------------------------------------------------------
template<int MODE>
__global__ __launch_bounds__(256, 2)
void conv_mfma(const ushortT* __restrict__ xin,
               const ushortT* __restrict__ wt,
               const float* __restrict__ bias,
               const float* __restrict__ scale,
               const float* __restrict__ shift,
               const float* __restrict__ att,
               const ushortT* __restrict__ addsrc,
               ushortT* __restrict__ outb,
               float* __restrict__ outf)
{
    __shared__ __align__(16) ushortT xs[480*64];     // 61,440 B (16 rows x 30 cols)
    __shared__ __align__(16) ushortT wsA[2][4096];   // dbuf [64 oc][64 ic], swizzled

    const int tid  = threadIdx.x;
    const int lane = tid & 63;
    const int ph   = tid >> 6;        // wave = pixel quarter (0..3)
    const int lrow = lane & 15;
    const int lgrp = lane >> 4;

    const int bid = blockIdx.x;       // 512 blocks, 1-D
    const int oct = bid >> 6;
    const int g   = bid & 63;         // g%8 == XCD for all 8 octile siblings
    const int b   = g >> 1;
    const int sh  = g & 1;
    const int oc0 = oct * 64;

    float a0 = 0.f, a1 = 0.f, a2 = 0.f;
    if (MODE != 0) { a0 = att[b*3+0]; a1 = att[b*3+1]; a2 = att[b*3+2]; }

    int pq[7];
#pragma unroll
    for (int nf = 0; nf < 7; ++nf) {
        int q = ph*98 + nf*16 + lrow;
        int qc = q < 392 ? q : 391;
        int r = qc / 28;
        pq[nf] = r*30 + (qc - r*28);
    }

    int afoff[2][4];
#pragma unroll
    for (int kk = 0; kk < 2; ++kk)
#pragma unroll
        for (int mf = 0; mf < 4; ++mf) {
            int ocl = mf*16 + lrow;
            afoff[kk][mf] = (ocl*8 + ((kk*4+lgrp) ^ (ocl&7)))*8;
        }

    int woff[2], wdst[2];
#pragma unroll
    for (int i = 0; i < 2; ++i) {
        int j = tid + i*256;
        int ocl = j >> 3, o = j & 7;
        woff[i] = ocl*CIN + o*8;
        wdst[i] = (ocl*8 + (o ^ (ocl&7)))*8;
    }

    f32x4 acc[4][7];
#pragma unroll
    for (int mf = 0; mf < 4; ++mf)
#pragma unroll
        for (int nf = 0; nf < 7; ++nf) acc[mf][nf] = (f32x4)0.f;

    const ushortT* xb = xin + (size_t)b * PIX * CIN;
    const size_t BANKS = (size_t)9*HIDC*CIN;

    auto stage_x = [&](int ic0) {
#pragma unroll
        for (int i = 0; i < 15; ++i) {
            int j = tid + i*256;           // 3840 = 15*256 exact
            int p = j >> 3, o = j & 7;
            int row = p / 30, col = p - row*30;
            int gh = sh*14 + row - 1, gw = col - 1;
            uint4 val = make_uint4(0u,0u,0u,0u);
            if ((unsigned)gh < 28u && (unsigned)gw < 28u)
                val = *(const uint4*)(xb + ((size_t)(gh*28 + gw)*CIN + ic0 + o*8));
            *(uint4*)(xs + (size_t)((p*8 + (o ^ (p&7)))*8)) = val;
        }
    };

    // ---- prologue: stage x(ch0) and weights(k=0) ----
    stage_x(0);
    {
        const ushortT* wA = wt + (size_t)oc0*CIN;    // tap 0, ic-chunk 0
#pragma unroll
        for (int i = 0; i < 2; ++i) {
            uint4 v0 = *(const uint4*)(wA + woff[i]);
            uint4 val = v0;
            if (MODE != 0) {
                uint4 v1 = *(const uint4*)(wA + woff[i] + BANKS);
                uint4 v2 = *(const uint4*)(wA + woff[i] + 2*BANKS);
                val = blend4(v0, v1, v2, a0, a1, a2);
            }
            *(uint4*)(&wsA[0][0] + wdst[i]) = val;
        }
    }
    __syncthreads();

    // ---- main K-loop: 72 steps ----
    uint4 p0[2], p1[2], p2[2];
    for (int k = 0; k < 72; ++k) {
        const int ch  = k / 9;
        const int t   = k - ch*9;
        const int cur = k & 1;
        const bool pf = (k < 71);
        const int kn  = k + 1;
        const int chn = kn / 9, tn = kn - chn*9;

        if (pf) {
            const ushortT* wA = wt + ((size_t)tn*HIDC + oc0)*CIN + chn*64;
#pragma unroll
            for (int i = 0; i < 2; ++i) {
                p0[i] = *(const uint4*)(wA + woff[i]);
                if (MODE != 0) {
                    p1[i] = *(const uint4*)(wA + woff[i] + BANKS);
                    p2[i] = *(const uint4*)(wA + woff[i] + 2*BANKS);
                }
            }
        }

        const int dh = (t >= 6) ? 2 : (t >= 3 ? 1 : 0);
        const int dw = t - dh*3;
        const int doff = dh*30 + dw;
        const ushortT* wbuf = &wsA[cur][0];
#pragma unroll
        for (int kk = 0; kk < 2; ++kk) {
            const int ob = kk*4 + lgrp;
            s16x8 af[4];
#pragma unroll
            for (int mf = 0; mf < 4; ++mf)
                af[mf] = *(const s16x8*)(wbuf + afoff[kk][mf]);
#pragma unroll
            for (int nf = 0; nf < 7; ++nf) {
                int pp = pq[nf] + doff;
                s16x8 bv = *(const s16x8*)(xs + (size_t)((pp*8 + (ob ^ (pp&7)))*8));
#pragma unroll
                for (int mf = 0; mf < 4; ++mf)
                    acc[mf][nf] = __builtin_amdgcn_mfma_f32_16x16x32_bf16(af[mf], bv, acc[mf][nf], 0, 0, 0);
            }
        }

        if (pf) {
            ushortT* wb = &wsA[cur^1][0];
#pragma unroll
            for (int i = 0; i < 2; ++i) {
                uint4 val;
                if (MODE == 0) val = p0[i];
                else           val = blend4(p0[i], p1[i], p2[i], a0, a1, a2);
                *(uint4*)(wb + wdst[i]) = val;
            }
            if (t == 8) {
                __syncthreads();
                stage_x(chn*64);
            }
        }
        __syncthreads();
    }

    // ---- epilogue ----
    const int q0 = ph * 98;
#pragma unroll
    for (int mf = 0; mf < 4; ++mf) {
        const int oc = oc0 + mf*16 + lgrp*4;
        float sc[4], shv[4];
#pragma unroll
        for (int jj = 0; jj < 4; ++jj) {
            if (MODE == 0) { sc[jj] = 1.f; shv[jj] = bias[oc+jj]; }
            else           { sc[jj] = scale[oc+jj]; shv[jj] = shift[oc+jj]; }
        }
#pragma unroll
        for (int nf = 0; nf < 7; ++nf) {
            const int qrel = nf*16 + lrow;
            if (qrel < 98) {
                const int p = sh*392 + q0 + qrel;
                f32x4 a = acc[mf][nf];
                if (MODE == 2) {
                    const ushortT* id = addsrc + ((size_t)b*PIX + p)*CIN + oc;
                    ushort4 iv = *(const ushort4*)id;
                    float v0 = fmaxf(a.x*sc[0] + shv[0] + bf2f(iv.x), 0.f);
                    float v1 = fmaxf(a.y*sc[1] + shv[1] + bf2f(iv.y), 0.f);
                    float v2 = fmaxf(a.z*sc[2] + shv[2] + bf2f(iv.z), 0.f);
                    float v3 = fmaxf(a.w*sc[3] + shv[3] + bf2f(iv.w), 0.f);
                    float* op = outf + ((size_t)b*HIDC + oc)*PIX + p;
                    op[0*PIX] = v0; op[1*PIX] = v1; op[2*PIX] = v2; op[3*PIX] = v3;
                } else {
                    float v0 = fmaxf(a.x*sc[0] + shv[0], 0.f);
                    float v1 = fmaxf(a.y*sc[1] + shv[1], 0.f);
                    float v2 = fmaxf(a.z*sc[2] + shv[2], 0.f);
                    float v3 = fmaxf(a.w*sc[3] + shv[3], 0.f);
                    ushort4 o4;
                    o4.x = (ushortT)f2bf_rne(v0); o4.y = (ushortT)f2bf_rne(v1);
                    o4.z = (ushortT)f2bf_rne(v2); o4.w = (ushortT)f2bf_rne(v3);
                    *(ushort4*)(outb + ((size_t)b*PIX + p)*CIN + oc) = o4;
                }
            }
        }
    }
}

// ---------------------------------------------------------------------------
// fallback f32 direct conv (used only if ws_size too small)
// ---------------------------------------------------------------------------
template<int MODE>
__global__ __launch_bounds__(256)
void conv3x3_kernel(const float* __restrict__ x,
                    const float* __restrict__ w,
                    const float* __restrict__ bias,
                    const float* __restrict__ att,
                    const float* __restrict__ bnscale,
                    const float* __restrict__ bnshift,
                    const float* __restrict__ addsrc,
                    float* __restrict__ out)
{
    const int tid = threadIdx.x;
    const int o0  = blockIdx.x * 8;
    const int b   = blockIdx.y;
    __shared__ float xsb[30*30];
    __shared__ float wsm[72];
    float a0 = 0.f, a1 = 0.f, a2 = 0.f;
    if (MODE != 0) { a0 = att[b*3+0]; a1 = att[b*3+1]; a2 = att[b*3+2]; }
    float acc[8][4];
#pragma unroll
    for (int o = 0; o < 8; ++o)
#pragma unroll
        for (int s = 0; s < 4; ++s) acc[o][s] = 0.f;
    const float* xbp = x + (size_t)b * CIN * PIX;
    for (int i = 0; i < CIN; ++i) {
        const float* xc = xbp + (size_t)i * PIX;
        for (int idx = tid; idx < 900; idx += 256) {
            int r = idx / 30, c = idx - r*30;
            float v = 0.f;
            if (r >= 1 && r <= HP && c >= 1 && c <= HP) v = xc[(r-1)*HP + (c-1)];
            xsb[idx] = v;
        }
        if (tid < 72) {
            int o = tid / 9, tap = tid - o*9;
            float wv;
            if (MODE == 0) wv = w[((size_t)(o0+o)*CIN + i)*9 + tap];
            else {
                size_t base = ((size_t)(o0+o)*CIN + i)*9 + tap;
                size_t bank = (size_t)HIDC*CIN*9;
                wv = a0*w[base] + a1*w[base+bank] + a2*w[base+2*bank];
            }
            wsm[tid] = wv;
        }
        __syncthreads();
        float xwin[4][9];
#pragma unroll
        for (int s = 0; s < 4; ++s) {
            int p = tid + s*256; if (p > PIX-1) p = PIX-1;
            int h = p / HP, wc = p - h*HP;
#pragma unroll
            for (int t = 0; t < 9; ++t) {
                int dh = t/3, dw = t - dh*3;
                xwin[s][t] = xsb[(h+dh)*30 + (wc+dw)];
            }
        }
#pragma unroll
        for (int o = 0; o < 8; ++o) {
            float wr[9];
#pragma unroll
            for (int t = 0; t < 9; ++t) wr[t] = wsm[o*9+t];
#pragma unroll
            for (int s = 0; s < 4; ++s) {
                float sum = acc[o][s];
#pragma unroll
                for (int t = 0; t < 9; ++t) sum = fmaf(wr[t], xwin[s][t], sum);
                acc[o][s] = sum;
            }
        }
        __syncthreads();
    }
#pragma unroll
    for (int s = 0; s < 4; ++s) {
        int p = tid + s*256;
        if (p >= PIX) continue;
#pragma unroll
        for (int o = 0; o < 8; ++o) {
            int oc = o0 + o;
            float v = acc[o][s];
            if (MODE == 0) v += bias[oc];
            else           v = v * bnscale[oc] + bnshift[oc];
            if (MODE == 2) v += addsrc[((size_t)b*HIDC + oc)*PIX + p];
            v = fmaxf(v, 0.f);
            out[((size_t)b*HIDC + oc)*PIX + p] = v;
        }
    }
}

// ---------------------------------------------------------------------------
// statistics branch: stat1 fused with cls, single pass (25 vals in regs)
// ---------------------------------------------------------------------------
__global__ __launch_bounds__(256)
void stat1cls_kernel(const float* __restrict__ fs, float* __restrict__ part,
                     int* __restrict__ cls)
{
    const int b = blockIdx.y, chunk = blockIdx.x, tid = threadIdx.x;
    const float* f = fs + (size_t)b * NPCH * HS2;
    const int lo = chunk * 14 * HS, hi = lo + 14 * HS;
    float s0=0.f, s1=0.f, s2=0.f, s3=0.f;
    for (int pos = lo + tid; pos < hi; pos += 256) {
        float f25[NPCH];
#pragma unroll
        for (int c = 0; c < NPCH; ++c) f25[c] = f[(size_t)c*HS2 + pos];
        float t0=-1e30f, t1=-1e30f, t2=-1e30f, t3=-1e30f;
        int bi = 0;
#pragma unroll
        for (int c = 0; c < NPCH; ++c) {
            float v = f25[c];
            if      (v > t0) { t3=t2; t2=t1; t1=t0; t0=v; bi=c; }
            else if (v > t1) { t3=t2; t2=t1; t1=v; }
            else if (v > t2) { t3=t2; t2=v; }
            else if (v > t3) { t3=v; }
        }
        cls[(size_t)b*HS2 + pos] = bi;
        float denom = 0.f;
#pragma unroll
        for (int c = 0; c < NPCH; ++c) denom += expf(f25[c] - t0);
        float inv = 1.f / denom;
        s0 += inv;
        s1 += expf(t1 - t0) * inv;
        s2 += expf(t2 - t0) * inv;
        s3 += expf(t3 - t0) * inv;
    }
    __shared__ float red[256];
    float vals[4] = {s0, s1, s2, s3};
    for (int j = 0; j < 4; ++j) {
        red[tid] = vals[j];
        __syncthreads();
        for (int off = 128; off; off >>= 1) {
            if (tid < off) red[tid] += red[tid + off];
            __syncthreads();
        }
        if (tid == 0) part[((size_t)b*8 + chunk)*4 + j] = red[0];
        __syncthreads();
    }
}

// fused row+col masked-std stats
#define RB 21504
#define CB 336
__global__ __launch_bounds__(256)
void rowcolstat_kernel(const float* __restrict__ u, const float* __restrict__ v,
                       const int* __restrict__ cls,
                       float* __restrict__ uvar, float* __restrict__ vvar)
{
    if (blockIdx.x < RB) {
        int wid = blockIdx.x*4 + (threadIdx.x >> 6);
        int lane = threadIdx.x & 63;
        int h = wid % HS, t = wid / HS, c = t % 24, b = t / 24;
        const int*   cr = cls + (size_t)b*HS2 + (size_t)h*HS;
        const float* ur = u + (((size_t)b*NPCH + c + 1)*HS + h)*HS;
        float cnt = 0.f, s = 0.f, s2 = 0.f;
        for (int wc = lane; wc < HS; wc += 64) {
            if (cr[wc] == c + 1) { float vv = ur[wc]; cnt += 1.f; s += vv; s2 += vv*vv; }
        }
        for (int off = 32; off; off >>= 1) {
            cnt += __shfl_down(cnt, off);
            s   += __shfl_down(s, off);
            s2  += __shfl_down(s2, off);
        }
        if (lane == 0) {
            float mean = s / cnt;
            uvar[wid] = sqrtf(fmaxf(s2/cnt - mean*mean, 0.f));
        }
    } else {
        int idx = (blockIdx.x - RB)*256 + threadIdx.x;
        if (idx >= NB*24*HS) return;
        int wc = idx % HS, t = idx / HS, c = t % 24, b = t / 24;
        const int*   cbase = cls + (size_t)b*HS2 + wc;
        const float* vbase = v + (((size_t)b*NPCH + c + 1)*HS)*HS + wc;
        float cnt = 0.f, s = 0.f, s2 = 0.f;
        for (int h = 0; h < HS; ++h) {
            if (cbase[(size_t)h*HS] == c + 1) {
                float val = vbase[(size_t)h*HS];
                cnt += 1.f; s += val; s2 += val*val;
            }
        }
        float mean = s / cnt;
        vvar[idx] = sqrtf(fmaxf(s2/cnt - mean*mean, 0.f));
    }
}

// partial over 8 position segments -> pooled2p[b*8+seg] (sum, undivided)
__global__ __launch_bounds__(256)
void stat2_kernel(const float* __restrict__ uvar, const float* __restrict__ vvar,
                  float* __restrict__ pooled2p)
{
    const int b = blockIdx.x, seg = blockIdx.y, tid = threadIdx.x;
    __shared__ float us[24*HS], vs[24*HS], red[256];
    for (int i = tid; i < 24*HS; i += 256) {
        us[i] = uvar[(size_t)b*24*HS + i];
        vs[i] = vvar[(size_t)b*24*HS + i];
    }
    __syncthreads();
    float local = 0.f;
    const int lo = seg*1568, hi = lo + 1568;
    for (int pos = lo + tid; pos < hi; pos += 256) {
        int h = pos / HS, wc = pos - h*HS;
        float sum = 0.f;
        for (int c = 0; c < 24; ++c) sum += sqrtf(us[c*HS+h] * vs[c*HS+wc]);
        local += expf(-sum);
    }
    red[tid] = local;
    __syncthreads();
    for (int off = 128; off; off >>= 1) {
        if (tid < off) red[tid] += red[tid + off];
        __syncthreads();
    }
    if (tid == 0) pooled2p[b*8 + seg] = red[0];
}

__global__ __launch_bounds__(256)
void mlp_kernel(const float* __restrict__ part, const float* __restrict__ pooled2p,
                const float* __restrict__ a1w1, const float* __restrict__ a1b1,
                const float* __restrict__ a1w2, const float* __restrict__ a1b2,
                const float* __restrict__ a2w1, const float* __restrict__ a2b1,
                const float* __restrict__ a2w2, const float* __restrict__ a2b2,
                const float* __restrict__ bn1g, const float* __restrict__ bn1b,
                const float* __restrict__ bn1m, const float* __restrict__ bn1v,
                const float* __restrict__ bn2g, const float* __restrict__ bn2b,
                const float* __restrict__ bn2m, const float* __restrict__ bn2v,
                float* __restrict__ att1, float* __restrict__ att2,
                float* __restrict__ bnsc)
{
    const int tid = threadIdx.x;
    if (tid < NB) {
        int b = tid;
        float p[5]; float tot = 0.f;
        for (int j = 0; j < 4; ++j) {
            float s = 0.f;
            for (int ch = 0; ch < 8; ++ch) s += part[((size_t)b*8 + ch)*4 + j];
            p[j] = s / (float)HS2; tot += p[j];
        }
        p[4] = tot * 0.25f;
        float lg[3] = {a1b2[0], a1b2[1], a1b2[2]};
        for (int j = 0; j < ATTH; ++j) {
            float hv = a1b1[j];
            for (int t = 0; t < 5; ++t) hv += a1w1[j*5+t] * p[t];
            hv = fmaxf(hv, 0.f);
            for (int k = 0; k < 3; ++k) lg[k] += a1w2[k*ATTH+j] * hv;
        }
        float mx = fmaxf(fmaxf(lg[0], lg[1]), lg[2]);
        float e0 = expf(lg[0]-mx), e1 = expf(lg[1]-mx), e2 = expf(lg[2]-mx);
        float inv = 1.f / (e0+e1+e2);
        att1[b*3+0] = e0*inv; att1[b*3+1] = e1*inv; att1[b*3+2] = e2*inv;
    } else if (tid < 2*NB) {
        int b = tid - NB;
        float psum = 0.f;
        for (int j = 0; j < 8; ++j) psum += pooled2p[b*8 + j];
        float p = psum / (float)HS2;
        float lg[3] = {a2b2[0], a2b2[1], a2b2[2]};
        for (int j = 0; j < ATTH; ++j) {
            float hv = fmaxf(a2b1[j] + a2w1[j] * p, 0.f);
            for (int k = 0; k < 3; ++k) lg[k] += a2w2[k*ATTH+j] * hv;
        }
        float mx = fmaxf(fmaxf(lg[0], lg[1]), lg[2]);
        float e0 = expf(lg[0]-mx), e1 = expf(lg[1]-mx), e2 = expf(lg[2]-mx);
        float inv = 1.f / (e0+e1+e2);
        att2[b*3+0] = e0*inv; att2[b*3+1] = e1*inv; att2[b*3+2] = e2*inv;
    }
    for (int o = tid; o < HIDC; o += 256) {
        float sc1 = bn1g[o] / sqrtf(bn1v[o] + BN_EPS);
        bnsc[o]          = sc1;
        bnsc[512 + o]    = bn1b[o] - bn1m[o]*sc1;
        float sc2 = bn2g[o] / sqrtf(bn2v[o] + BN_EPS);
        bnsc[1024 + o]   = sc2;
        bnsc[1536 + o]   = bn2b[o] - bn2m[o]*sc2;
    }
}

// ---------------------------------------------------------------------------
extern "C" void kernel_launch(void* const* d_in, const int* in_sizes, int n_in,
                              void* d_out, int out_size, void* d_ws, size_t ws_size,
                              hipStream_t stream)
{
    (void)in_sizes; (void)n_in; (void)out_size;
    const float* features = (const float*)d_in[0];
    const float* fine_segm= (const float*)d_in[1];
    const float* u        = (const float*)d_in[2];
    const float* v        = (const float*)d_in[3];
    const float* conv1_w  = (const float*)d_in[4];
    const float* conv1_b  = (const float*)d_in[5];
    const float* conv2_w  = (const float*)d_in[6];
    const float* conv2_b  = (const float*)d_in[7];
    const float* a1w1     = (const float*)d_in[8];
    const float* a1b1     = (const float*)d_in[9];
    const float* a1w2     = (const float*)d_in[10];
    const float* a1b2     = (const float*)d_in[11];
    const float* dyn1_w   = (const float*)d_in[12];
    const float* a2w1     = (const float*)d_in[13];
    const float* a2b1     = (const float*)d_in[14];
    const float* a2w2     = (const float*)d_in[15];
    const float* a2b2     = (const float*)d_in[16];
    const float* dyn2_w   = (const float*)d_in[17];
    const float* bn1g     = (const float*)d_in[18];
    const float* bn1b     = (const float*)d_in[19];
    const float* bn1m     = (const float*)d_in[20];
    const float* bn1v     = (const float*)d_in[21];
    const float* bn2g     = (const float*)d_in[22];
    const float* bn2b     = (const float*)d_in[23];
    const float* bn2m     = (const float*)d_in[24];
    const float* bn2v     = (const float*)d_in[25];

    const size_t XB_BYTES = (size_t)NB*PIX*CIN*2;        // 25,690,112
    const size_t WT_BYTES = (size_t)3*9*HIDC*CIN*2;      // 14,155,776
    const size_t NEED = XB_BYTES*2 + WT_BYTES + 2308096;
    const size_t WSLOT = (size_t)9*HIDC*CIN;             // elements per slot

    if (ws_size >= NEED) {
        char* wsb = (char*)d_ws;
        ushortT* xbuf = (ushortT*)wsb;                      // features NHWC, then y1
        ushortT* x2   = (ushortT*)(wsb + XB_BYTES);         // identity
        ushortT* wt   = (ushortT*)(wsb + 2*XB_BYTES);       // transformed weights (3 slots)
        float* sm     = (float*)(wsb + 2*XB_BYTES + WT_BYTES);
        float* part    = sm;  sm += 1024;
        float* pooled2 = sm;  sm += 256;
        float* att1    = sm;  sm += 96;
        float* att2    = sm;  sm += 96;
        float* bnsc    = sm;  sm += 2048;
        float* uvar    = sm;  sm += NB*24*HS;
        float* vvar    = sm;  sm += NB*24*HS;
        int*   cls     = (int*)sm;
        ushortT* x1    = (ushortT*)d_out;   // 25.7MB scratch inside 51.4MB d_out

        // conv backbone front half (XCD-affinity 1-D grid)
        nchw2nhwc_bf16<<<dim3(13, 8, NB), 256, 0, stream>>>(features, xbuf);
        wtrans2_kernel<<<dim3(512, 2), 256, 0, stream>>>(conv1_w, conv2_w, wt);
        conv_mfma<0><<<512, 256, 0, stream>>>(
            xbuf, wt, conv1_b, nullptr, nullptr, nullptr, nullptr, x1, nullptr);
        conv_mfma<0><<<512, 256, 0, stream>>>(
            x1, wt + WSLOT, conv2_b, nullptr, nullptr, nullptr, nullptr, x2, nullptr);

        // statistics branch
        stat1cls_kernel<<<dim3(8, NB), 256, 0, stream>>>(fine_segm, part, cls);
        rowcolstat_kernel<<<RB + CB, 256, 0, stream>>>(u, v, cls, uvar, vvar);
        stat2_kernel<<<dim3(NB, 8), 256, 0, stream>>>(uvar, vvar, pooled2);
        mlp_kernel<<<1, 256, 0, stream>>>(part, pooled2,
            a1w1, a1b1, a1w2, a1b2, a2w1, a2b1, a2w2, a2b2,
            bn1g, bn1b, bn1m, bn1v, bn2g, bn2b, bn2m, bn2v,
            att1, att2, bnsc);

        // dynamic convs (XCD-affinity 1-D grid)
        wtrans_kernel<<<dim3(512, 3), 256, 0, stream>>>(dyn1_w, wt);
        conv_mfma<1><<<512, 256, 0, stream>>>(
            x2, wt, nullptr, bnsc, bnsc + 512, att1, nullptr, xbuf, nullptr);
        wtrans_kernel<<<dim3(512, 3), 256, 0, stream>>>(dyn2_w, wt);
        conv_mfma<2><<<512, 256, 0, stream>>>(
            xbuf, wt, nullptr, bnsc + 1024, bnsc + 1536, att2, x2, nullptr, (float*)d_out);
    } else {
        // fallback: f32 direct path
        const size_t BIG = (size_t)NB * HIDC * PIX;
        float* x1y1 = (float*)d_out;
        float* ws0  = (float*)d_ws;
        float* sm   = ws0 + BIG;
        float* part    = sm;  sm += 1024;
        float* pooled2 = sm;  sm += 256;
        float* att1    = sm;  sm += 96;
        float* att2    = sm;  sm += 96;
        float* bnsc    = sm;  sm += 2048;
        float* uvar    = sm;  sm += NB*24*HS;
        float* vvar    = sm;  sm += NB*24*HS;
        int*   cls     = (int*)sm;

        conv3x3_kernel<0><<<dim3(64, NB), 256, 0, stream>>>(
            features, conv1_w, conv1_b, nullptr, nullptr, nullptr, nullptr, x1y1);
        conv3x3_kernel<0><<<dim3(64, NB), 256, 0, stream>>>(
            x1y1, conv2_w, conv2_b, nullptr, nullptr, nullptr, nullptr, ws0);
        stat1cls_kernel<<<dim3(8, NB), 256, 0, stream>>>(fine_segm, part, cls);
        rowcolstat_kernel<<<RB + CB, 256, 0, stream>>>(u, v, cls, uvar, vvar);
        stat2_kernel<<<dim3(NB, 8), 256, 0, stream>>>(uvar, vvar, pooled2);
        mlp_kernel<<<1, 256, 0, stream>>>(part, pooled2,
            a1w1, a1b1, a1w2, a1b2, a2w1, a2b1, a2w2, a2b2,
            bn1g, bn1b, bn1m, bn1v, bn2g, bn2b, bn2m, bn2v,
            att1, att2, bnsc);
        conv3x3_kernel<1><<<dim3(64, NB), 256, 0, stream>>>(
            ws0, dyn1_w, nullptr, att1, bnsc, bnsc + 512, nullptr, x1y1);
        conv3x3_kernel<2><<<dim3(64, NB), 256, 0, stream>>>(
            x1y1, dyn2_w, nullptr, att2, bnsc + 1024, bnsc + 1536, ws0, ws0);
        hipMemcpyAsync(d_out, ws0, BIG * sizeof(float), hipMemcpyDeviceToDevice, stream);
    }
}